// Round 1
// baseline (248.743 us; speedup 1.0000x reference)
//
#include <hip/hip_runtime.h>
#include <cstdint>

// Local nearest-neighbor VOS features, MI355X round 0.
//
// d(i,j,o) = min over (dy,dx) in 31x31 window of
//            ( in-frame && label==gt[o]  ?  ||Q[i,j]-P[i+dy-15,j+dx-15]||^2 : 1.0 )
// Key identity: ||q-p||^2 = |q|^2 + |p|^2 - 2 q.p  -> only the dot field is hot.
// Reference's 1e20 embedding pad is irrelevant: mask pad is False, so every
// out-of-frame offset contributes exactly 1.0 (we emulate with a sentinel label).

#define HW    128
#define NC    100
#define NC4   25          // float4 chunks per pixel (100 floats, 400B => 16B aligned)
#define MD    15
#define KW    31
#define NOBJ  3
#define RTILE 4           // query rows per block
#define NCOLS 94          // 64 lane columns + 30 halo
#define LSTR  108         // LDS col stride in floats: 432B (16B aligned, bank step 12 -> <=2-way)
#define RSPAN 34          // P rows touched by a 4-row query stripe: [i0-15, i0+18]
#define RCHUNK 3
#define NCHUNK 12         // ceil(34/3)
#define BIGF  1e30f

// ---------------- prep: |P|^2, |Q|^2 per pixel, init output to +inf ----------------
__global__ __launch_bounds__(256) void vos_prep(
    const float* __restrict__ P, const float* __restrict__ Q,
    float* __restrict__ y2, float* __restrict__ x2, unsigned int* __restrict__ out)
{
    int p = blockIdx.x * 256 + threadIdx.x;          // exactly 16384 threads
    const float4* pr = (const float4*)(P + (size_t)p * NC);
    const float4* qr = (const float4*)(Q + (size_t)p * NC);
    float sy = 0.f, sx = 0.f;
#pragma unroll
    for (int i = 0; i < NC4; ++i) {
        float4 a = pr[i];
        sy = fmaf(a.x, a.x, sy); sy = fmaf(a.y, a.y, sy);
        sy = fmaf(a.z, a.z, sy); sy = fmaf(a.w, a.w, sy);
        float4 b = qr[i];
        sx = fmaf(b.x, b.x, sx); sx = fmaf(b.y, b.y, sx);
        sx = fmaf(b.z, b.z, sx); sx = fmaf(b.w, b.w, sx);
    }
    y2[p] = sy;                                      // prev-frame (P) norms
    x2[p] = sx;                                      // query (Q) norms
    out[p*3+0] = 0x7F800000u;                        // +inf bits; all candidates >=0,
    out[p*3+1] = 0x7F800000u;                        // so uint atomicMin == float min
    out[p*3+2] = 0x7F800000u;
}

// ---------------- main: register-blocked window dot + masked min ----------------
__global__ __launch_bounds__(64, 1) void vos_main(
    const float* __restrict__ P, const float* __restrict__ Q,
    const int* __restrict__ labels, const int* __restrict__ gt,
    const float* __restrict__ y2, const float* __restrict__ x2,
    unsigned int* __restrict__ out)
{
    __shared__ float Plds[NCOLS * LSTR];             // 94*108*4 = 40.6 KB
    __shared__ float y2lds[NCOLS];
    __shared__ int   lblds[NCOLS];

    const int lane = threadIdx.x;                    // 0..63 = query column offset
    const int bid  = blockIdx.x;
    const int jh   = bid & 1;                        // 2 column halves
    const int it   = (bid >> 1) & 31;                // 32 row stripes
    const int ck   = bid >> 6;                       // 12 P-row chunks
    const int i0   = it * RTILE;
    const int j0   = jh * 64;
    const int j    = j0 + lane;

    const int g0 = gt[0], g1 = gt[1], g2 = gt[2];

    float x2p[RTILE];
#pragma unroll
    for (int p = 0; p < RTILE; ++p) x2p[p] = x2[(i0 + p) * HW + j];

    float m[RTILE][NOBJ];
#pragma unroll
    for (int p = 0; p < RTILE; ++p) {
        m[p][0] = BIGF; m[p][1] = BIGF; m[p][2] = BIGF;
    }

    const int r_begin = i0 - MD + ck * RCHUNK;
    const int r_count = min(RCHUNK, (i0 + MD + RTILE - 1) - r_begin + 1); // clip to i0+18

    for (int ri = 0; ri < r_count; ++ri) {
        const int r = r_begin + ri;

        __syncthreads();                             // protect prior iter's LDS reads
        {
            // Stage P row r, cols j0-15 .. j0+78, into LDS (col-major, padded stride).
            // OOB rows/cols: clamped loads (finite garbage) — never selected, because
            // the sentinel label below forces candidate 1.0 for those offsets.
            const int gr = min(max(r, 0), HW - 1);
            for (int t = lane; t < NCOLS * NC4; t += 64) {
                unsigned ut  = (unsigned)t;
                int col = (int)(ut / NC4);
                int c4  = (int)(ut - (unsigned)col * NC4);
                int gcol = j0 - 15 + col;
                int gc   = min(max(gcol, 0), HW - 1);
                float4 v = *(const float4*)(P + ((size_t)(gr * HW + gc)) * NC + c4 * 4);
                *(float4*)(&Plds[col * LSTR + c4 * 4]) = v;
            }
            for (int t = lane; t < NCOLS; t += 64) {
                int gcol = j0 - 15 + t;
                bool inb = (r >= 0) & (r < HW) & (gcol >= 0) & (gcol < HW);
                int gc = min(max(gcol, 0), HW - 1);
                y2lds[t] = y2[gr * HW + gc];
                lblds[t] = inb ? labels[gr * HW + gc] : -1;   // gt_ids are arange(3): -1 never matches
            }
        }
        __syncthreads();

        // acc[p][dx] = dot(Q[i0+p, j], P[r, j+dx-15]) — each ds_read_b128 feeds 16 FMAs
        float acc[RTILE][KW];
#pragma unroll
        for (int p = 0; p < RTILE; ++p)
#pragma unroll
            for (int dx = 0; dx < KW; ++dx) acc[p][dx] = 0.f;

        const float* qb0 = Q + ((size_t)((i0 + 0) * HW + j)) * NC;
        const float* qb1 = Q + ((size_t)((i0 + 1) * HW + j)) * NC;
        const float* qb2 = Q + ((size_t)((i0 + 2) * HW + j)) * NC;
        const float* qb3 = Q + ((size_t)((i0 + 3) * HW + j)) * NC;

        for (int c4 = 0; c4 < NC4; ++c4) {
            float4 qv[RTILE];
            qv[0] = *(const float4*)(qb0 + c4 * 4);
            qv[1] = *(const float4*)(qb1 + c4 * 4);
            qv[2] = *(const float4*)(qb2 + c4 * 4);
            qv[3] = *(const float4*)(qb3 + c4 * 4);
#pragma unroll
            for (int dx = 0; dx < KW; ++dx) {
                float4 pv = *(const float4*)(&Plds[(lane + dx) * LSTR + c4 * 4]);
#pragma unroll
                for (int p = 0; p < RTILE; ++p) {
                    acc[p][dx] = fmaf(qv[p].x, pv.x, acc[p][dx]);
                    acc[p][dx] = fmaf(qv[p].y, pv.y, acc[p][dx]);
                    acc[p][dx] = fmaf(qv[p].z, pv.z, acc[p][dx]);
                    acc[p][dx] = fmaf(qv[p].w, pv.w, acc[p][dx]);
                }
            }
        }

        // Epilogue: d = |q|^2 + |p|^2 - 2*dot, masked min per object.
        // Row-validity (dy in [0,30]) folded in branchlessly: invalid rows get +1e30
        // mixed into the additive term (1e30 +- O(1e3) rounds back to 1e30) and a
        // 1e30 "one" so they contribute nothing to the min.
        const int rr = r - i0;
        float x2b[RTILE], onep[RTILE];
#pragma unroll
        for (int p = 0; p < RTILE; ++p) {
            int dy = rr + MD - p;
            bool pval = (dy >= 0) & (dy <= 2 * MD);
            x2b[p]  = x2p[p] + (pval ? 0.f : BIGF);
            onep[p] = pval ? 1.f : BIGF;
        }
#pragma unroll
        for (int dx = 0; dx < KW; ++dx) {
            float yv = y2lds[lane + dx];
            int   lv = lblds[lane + dx];
            bool b0 = (lv == g0), b1 = (lv == g1), b2 = (lv == g2);
#pragma unroll
            for (int p = 0; p < RTILE; ++p) {
                float d = fmaf(acc[p][dx], -2.f, x2b[p] + yv);
                d = fmaxf(d, 0.f);                   // guard atomic-uint ordering
                m[p][0] = fminf(m[p][0], b0 ? d : onep[p]);
                m[p][1] = fminf(m[p][1], b1 ? d : onep[p]);
                m[p][2] = fminf(m[p][2], b2 ? d : onep[p]);
            }
        }
    }

    // Combine partial mins across r-chunks. All values nonneg => uint order == float order.
#pragma unroll
    for (int p = 0; p < RTILE; ++p) {
        unsigned int* op = out + ((size_t)((i0 + p) * HW + j)) * NOBJ;
        atomicMin(&op[0], __float_as_uint(m[p][0]));
        atomicMin(&op[1], __float_as_uint(m[p][1]));
        atomicMin(&op[2], __float_as_uint(m[p][2]));
    }
}

extern "C" void kernel_launch(void* const* d_in, const int* in_sizes, int n_in,
                              void* d_out, int out_size, void* d_ws, size_t ws_size,
                              hipStream_t stream) {
    const float* P      = (const float*)d_in[0];   // prev_frame_embedding [128,128,100]
    const float* Q      = (const float*)d_in[1];   // query_embedding      [128,128,100]
    const int*   labels = (const int*)d_in[2];     // prev_frame_labels    [128,128,1]
    const int*   gt     = (const int*)d_in[3];     // gt_ids [3]
    // d_in[4] = max_distance (always 15; kernel compiled for MD=15)

    float* y2 = (float*)d_ws;                      // 16384 floats
    float* x2 = y2 + HW * HW;                      // 16384 floats
    unsigned int* out = (unsigned int*)d_out;

    vos_prep<<<HW * HW / 256, 256, 0, stream>>>(P, Q, y2, x2, out);
    vos_main<<<2 * 32 * NCHUNK, 64, 0, stream>>>(P, Q, labels, gt, y2, x2, out);
}

// Round 2
// 124.216 us; speedup vs baseline: 2.0025x; 2.0025x over previous
//
#include <hip/hip_runtime.h>
#include <cstdint>

// Local NN VOS features via banded bf16-split MFMA GEMM. MI355X round 2.
//
// d(i,j,o) = min over |dy|<=15,|dx|<=15 of (in-frame && label==gt[o] ? ||Q[i,j]-P[i+dy,j+dx]||^2 : 1.0)
//          = clamp( min_valid( x2[q] + y2[p] - 2 Q.P ), 0, 1.0 )   [>=1 masked offset always exists]
// Dot field computed with mfma_f32_16x16x32_bf16, fp32 recovered by 2-way bf16 split
// (qh*ph + qh*pl + ql*ph; dropped ql*pl ~1e-4 abs error << 2e-2 threshold).

#define HW   128
#define NC   100
#define MD   15
#define NOBJ 3
#define BIGF 1e30f

typedef __attribute__((ext_vector_type(8))) short  short8;   // 8 x bf16 (4 VGPR)
typedef __attribute__((ext_vector_type(4))) float  floatx4;  // MFMA C/D

__device__ inline unsigned short bf16_rne(float x) {
    union { float f; unsigned u; } v; v.f = x;
    unsigned r = v.u + 0x7FFFu + ((v.u >> 16) & 1u);
    return (unsigned short)(r >> 16);
}
__device__ inline float bf16_up(unsigned short h) {
    union { unsigned u; float f; } v; v.u = ((unsigned)h) << 16; return v.f;
}
__device__ inline void split8(const float* v, short8& h, short8& l) {
#pragma unroll
    for (int j = 0; j < 8; ++j) {
        unsigned short hb = bf16_rne(v[j]);
        unsigned short lb = bf16_rne(v[j] - bf16_up(hb));
        h[j] = (short)hb; l[j] = (short)lb;
    }
}

// ---------------- prep: |P|^2, |Q|^2 per pixel, init output to +inf ----------------
__global__ __launch_bounds__(64) void vos_prep(
    const float* __restrict__ P, const float* __restrict__ Q,
    float* __restrict__ y2, float* __restrict__ x2, unsigned int* __restrict__ out)
{
    int p = blockIdx.x * 64 + threadIdx.x;            // 256 blocks x 64 thr = 16384 pixels
    const float4* pr = (const float4*)(P + (size_t)p * NC);
    const float4* qr = (const float4*)(Q + (size_t)p * NC);
    float sy = 0.f, sx = 0.f;
#pragma unroll
    for (int i = 0; i < NC / 4; ++i) {
        float4 a = pr[i];
        sy = fmaf(a.x, a.x, sy); sy = fmaf(a.y, a.y, sy);
        sy = fmaf(a.z, a.z, sy); sy = fmaf(a.w, a.w, sy);
        float4 b = qr[i];
        sx = fmaf(b.x, b.x, sx); sx = fmaf(b.y, b.y, sx);
        sx = fmaf(b.z, b.z, sx); sx = fmaf(b.w, b.w, sx);
    }
    y2[p] = sy;
    x2[p] = sx;
    out[p*3+0] = 0x7F800000u;                          // +inf bits (all results >= 0)
    out[p*3+1] = 0x7F800000u;
    out[p*3+2] = 0x7F800000u;
}

// ---------------- main: banded MFMA GEMM + masked min epilogue ----------------
// Block: 256 thr (4 waves), covers query rows {i0, i0+1} x all 128 cols.
// Wave w: q-cols [32w, 32w+32) as 2 M-tiles (uc) x 2 rows (ur) = 4 tile-units.
// Grid: 64 stripes x 8 r-chunks (4 P-rows each) = 512 blocks; atomicMin combine.
__global__ __launch_bounds__(256, 2) void vos_mfma(
    const float* __restrict__ P, const float* __restrict__ Q,
    const int* __restrict__ labels, const int* __restrict__ gt,
    const float* __restrict__ y2, const float* __restrict__ x2,
    unsigned int* __restrict__ out)
{
    // B operand LDS: P row r, split hi/lo, [col][k0..127] bf16, 16B-chunk XOR swizzle.
    // Exactly 64 KB -> 2 blocks/CU.
    __shared__ unsigned short Bh[128 * 128];
    __shared__ unsigned short Bl[128 * 128];

    const int tid  = threadIdx.x;
    const int lane = tid & 63;
    const int wv   = tid >> 6;          // wave 0..3
    const int quad = lane >> 4;         // 0..3
    const int n    = lane & 15;         // N index (P col within tile) in B and C layouts
    const int j0w  = wv * 32;

    const int stripe = blockIdx.x >> 3;
    const int ck     = blockIdx.x & 7;
    const int i0     = stripe * 2;

    const int g0 = gt[0], g1 = gt[1], g2 = gt[2];

    // ---- A fragments: Q split hi/lo. A layout: A[m=lane&15][k=quad*8+j].
    short8 Ah[2][2][4], Al[2][2][4];    // [uc][ur][kc]
    float  x2q[2][2][4];                // [uc][ur][reg]; C row m = quad*4+reg
#pragma unroll
    for (int uc = 0; uc < 2; ++uc)
#pragma unroll
    for (int ur = 0; ur < 2; ++ur) {
        const float* qp = Q + ((size_t)((i0 + ur) * HW + j0w + 16 * uc + n)) * NC;
#pragma unroll
        for (int kc = 0; kc < 3; ++kc) {
            float v[8];
            float4 a0 = *(const float4*)(qp + kc * 32 + quad * 8);
            float4 a1 = *(const float4*)(qp + kc * 32 + quad * 8 + 4);
            v[0]=a0.x; v[1]=a0.y; v[2]=a0.z; v[3]=a0.w;
            v[4]=a1.x; v[5]=a1.y; v[6]=a1.z; v[7]=a1.w;
            split8(v, Ah[uc][ur][kc], Al[uc][ur][kc]);
        }
        {   // kc=3: k = 96 + quad*8 + j; valid only quad==0 && j<4 (channels 96..99)
            float4 a = *(const float4*)(qp + 96);
            float v[8];
            v[0] = (quad == 0) ? a.x : 0.f;
            v[1] = (quad == 0) ? a.y : 0.f;
            v[2] = (quad == 0) ? a.z : 0.f;
            v[3] = (quad == 0) ? a.w : 0.f;
            v[4] = 0.f; v[5] = 0.f; v[6] = 0.f; v[7] = 0.f;
            split8(v, Ah[uc][ur][3], Al[uc][ur][3]);
        }
#pragma unroll
        for (int reg = 0; reg < 4; ++reg)
            x2q[uc][ur][reg] = x2[(i0 + ur) * HW + j0w + 16 * uc + quad * 4 + reg];
    }

    // Static band masks (side tiles are triangular): offset = 16*du + n - m, valid |off|<=15.
    bool bgt[4], blt[4];
#pragma unroll
    for (int reg = 0; reg < 4; ++reg) {
        int m = quad * 4 + reg;
        bgt[reg] = n > m;   // du = -1
        blt[reg] = n < m;   // du = +1
    }

    float mm[2][2][4][NOBJ];
#pragma unroll
    for (int uc = 0; uc < 2; ++uc)
#pragma unroll
    for (int ur = 0; ur < 2; ++ur)
#pragma unroll
    for (int reg = 0; reg < 4; ++reg) {
        mm[uc][ur][reg][0] = BIGF; mm[uc][ur][reg][1] = BIGF; mm[uc][ur][reg][2] = BIGF;
    }

    const int rbase = i0 - MD + ck * 4;
    for (int rr = 0; rr < 4; ++rr) {
        const int r = rbase + rr;
        if (r < 0 || r >= HW) continue;               // block-uniform: barrier count stays aligned

        __syncthreads();                               // previous iter's LDS reads done
        {   // ---- stage P row r as split bf16 into LDS (B layout, swizzled)
            const float* prow = P + (size_t)r * HW * NC;
#pragma unroll
            for (int it = 0; it < 8; ++it) {
                int t   = it * 256 + tid;              // 2048 (col, chunk) tasks
                int col = t >> 4, ch = t & 15;         // chunk = 8 channels (16B)
                float v[8];
#pragma unroll
                for (int j = 0; j < 8; ++j) v[j] = 0.f;
                if (ch < 12) {
                    float4 a0 = *(const float4*)(prow + col * NC + ch * 8);
                    float4 a1 = *(const float4*)(prow + col * NC + ch * 8 + 4);
                    v[0]=a0.x; v[1]=a0.y; v[2]=a0.z; v[3]=a0.w;
                    v[4]=a1.x; v[5]=a1.y; v[6]=a1.z; v[7]=a1.w;
                } else if (ch == 12) {                 // channels 96..99, rest zero-pad
                    float4 a0 = *(const float4*)(prow + col * NC + 96);
                    v[0]=a0.x; v[1]=a0.y; v[2]=a0.z; v[3]=a0.w;
                }
                short8 h, l; split8(v, h, l);
                int off = col * 128 + ((ch ^ (col & 7)) << 3);   // ushort units
                *(short8*)(Bh + off) = h;
                *(short8*)(Bl + off) = l;
            }
        }
        __syncthreads();

        const bool rv0 = (unsigned)(r - i0 + MD) <= 2u * MD;         // |r-i0|<=15
        const bool rv1 = (unsigned)(r - i0 - 1 + MD) <= 2u * MD;
        const int  ry  = r * HW;

#pragma unroll
        for (int t = 0; t < 4; ++t) {
            const int base = j0w + 16 * (t - 1);       // N-tile base P col
            if (base < 0 || base >= HW) continue;      // wave-uniform edge skip

            const int pcol = base + n;                 // this lane's P col
            float y2v = y2[ry + pcol];
            int   lab = labels[ry + pcol];
            float pen0 = (lab == g0) ? y2v : BIGF;
            float pen1 = (lab == g1) ? y2v : BIGF;
            float pen2 = (lab == g2) ? y2v : BIGF;

            floatx4 C[2][2];
#pragma unroll
            for (int uc = 0; uc < 2; ++uc)
#pragma unroll
            for (int ur = 0; ur < 2; ++ur) C[uc][ur] = (floatx4){0.f, 0.f, 0.f, 0.f};

#pragma unroll
            for (int kc = 0; kc < 4; ++kc) {
                int off = pcol * 128 + (((kc * 4 + quad) ^ (pcol & 7)) << 3);
                short8 bh = *(const short8*)(Bh + off);
                short8 bl = *(const short8*)(Bl + off);
#pragma unroll
                for (int uc = 0; uc < 2; ++uc) {
                    if (uc == 0 && t == 3) continue;   // tile-use sets: uc0 -> t in {0,1,2}
                    if (uc == 1 && t == 0) continue;   //               uc1 -> t in {1,2,3}
#pragma unroll
                    for (int ur = 0; ur < 2; ++ur) {
                        C[uc][ur] = __builtin_amdgcn_mfma_f32_16x16x32_bf16(Ah[uc][ur][kc], bh, C[uc][ur], 0, 0, 0);
                        C[uc][ur] = __builtin_amdgcn_mfma_f32_16x16x32_bf16(Ah[uc][ur][kc], bl, C[uc][ur], 0, 0, 0);
                        C[uc][ur] = __builtin_amdgcn_mfma_f32_16x16x32_bf16(Al[uc][ur][kc], bh, C[uc][ur], 0, 0, 0);
                    }
                }
            }

            // ---- epilogue: d = x2 + y2 - 2*dot, masked per-object running min
#pragma unroll
            for (int uc = 0; uc < 2; ++uc) {
                if (uc == 0 && t == 3) continue;
                if (uc == 1 && t == 0) continue;
                const int du = t - 1 - uc;             // -1, 0, +1 (compile-time)
#pragma unroll
                for (int ur = 0; ur < 2; ++ur) {
                    const bool rv = ur ? rv1 : rv0;
#pragma unroll
                    for (int reg = 0; reg < 4; ++reg) {
                        float tv = fmaf(C[uc][ur][reg], -2.f, x2q[uc][ur][reg]);
                        tv = rv ? tv : BIGF;
                        if (du == -1) tv = bgt[reg] ? tv : BIGF;
                        if (du == +1) tv = blt[reg] ? tv : BIGF;
                        mm[uc][ur][reg][0] = fminf(mm[uc][ur][reg][0], tv + pen0);
                        mm[uc][ur][reg][1] = fminf(mm[uc][ur][reg][1], tv + pen1);
                        mm[uc][ur][reg][2] = fminf(mm[uc][ur][reg][2], tv + pen2);
                    }
                }
            }
        }
    }

    // ---- min-reduce across the 16 N-lanes of each quad, then atomicMin combine
#pragma unroll
    for (int s = 1; s < 16; s <<= 1) {
#pragma unroll
        for (int uc = 0; uc < 2; ++uc)
#pragma unroll
        for (int ur = 0; ur < 2; ++ur)
#pragma unroll
        for (int reg = 0; reg < 4; ++reg)
#pragma unroll
        for (int o = 0; o < NOBJ; ++o)
            mm[uc][ur][reg][o] = fminf(mm[uc][ur][reg][o], __shfl_xor(mm[uc][ur][reg][o], s));
    }
    if (n == 0) {
#pragma unroll
        for (int uc = 0; uc < 2; ++uc)
#pragma unroll
        for (int ur = 0; ur < 2; ++ur)
#pragma unroll
        for (int reg = 0; reg < 4; ++reg) {
            const int qrow = i0 + ur;
            const int qcol = j0w + 16 * uc + quad * 4 + reg;
            unsigned int* op = out + ((size_t)(qrow * HW + qcol)) * NOBJ;
#pragma unroll
            for (int o = 0; o < NOBJ; ++o) {
                // clamp: d>=0 mathematically (uint order needs it); every (pixel,obj) has
                // >=1 masked offset in the full window -> result <= 1.0 exactly.
                float v = fminf(fmaxf(mm[uc][ur][reg][o], 0.f), 1.0f);
                atomicMin(op + o, __float_as_uint(v));
            }
        }
    }
}

extern "C" void kernel_launch(void* const* d_in, const int* in_sizes, int n_in,
                              void* d_out, int out_size, void* d_ws, size_t ws_size,
                              hipStream_t stream) {
    const float* P      = (const float*)d_in[0];   // prev_frame_embedding [128,128,100]
    const float* Q      = (const float*)d_in[1];   // query_embedding      [128,128,100]
    const int*   labels = (const int*)d_in[2];     // prev_frame_labels    [128,128,1]
    const int*   gt     = (const int*)d_in[3];     // gt_ids [3]
    // d_in[4] = max_distance (always 15; compiled for MD=15)

    float* y2 = (float*)d_ws;                      // 16384 floats
    float* x2 = y2 + HW * HW;                      // 16384 floats
    unsigned int* out = (unsigned int*)d_out;

    vos_prep<<<HW * HW / 64, 64, 0, stream>>>(P, Q, y2, x2, out);
    vos_mfma<<<64 * 8, 256, 0, stream>>>(P, Q, labels, gt, y2, x2, out);
}

// Round 3
// 121.060 us; speedup vs baseline: 2.0547x; 1.0261x over previous
//
#include <hip/hip_runtime.h>
#include <cstdint>

// Local NN VOS features via banded bf16-split MFMA GEMM. MI355X round 3.
//
// Round-3 change vs round 2: fp32->bf16 hi/lo split is done ONCE in vos_prep,
// written to workspace in operand-native layouts:
//   Pb [row][col][s][chunk^swz][8ch]  -- B-operand LDS image, 64 KB/row, swizzle baked in.
//        Main kernel stages a row with global_load_lds width=16 (zero VALU, async DMA).
//   Qa [row][tile][s][kc][quad][n][8ch] -- A-fragment layout; wave loads frags as
//        perfectly coalesced b128 global loads (zero VALU, no 400B-stride scatter).
// This removes the 17x-redundant per-block load+split staging that capped round 2
// (MfmaUtil 10%, 60% all-pipes-idle).
//
// Workspace requirement: 16.2 MB (y2 64K + x2 64K + Pb 8.39M + Qa 8.39M).

#define HW   128
#define NC   100
#define MD   15
#define NOBJ 3
#define BIGF 1e30f

typedef __attribute__((ext_vector_type(8))) short  short8;   // 8 x bf16 (4 VGPR)
typedef __attribute__((ext_vector_type(4))) float  floatx4;  // MFMA C/D

__device__ inline unsigned short bf16_rne(float x) {
    union { float f; unsigned u; } v; v.f = x;
    unsigned r = v.u + 0x7FFFu + ((v.u >> 16) & 1u);
    return (unsigned short)(r >> 16);
}
__device__ inline float bf16_up(unsigned short h) {
    union { unsigned u; float f; } v; v.u = ((unsigned)h) << 16; return v.f;
}
__device__ inline void split8v(const float* v, short8& h, short8& l) {
#pragma unroll
    for (int j = 0; j < 8; ++j) {
        unsigned short hb = bf16_rne(v[j]);
        unsigned short lb = bf16_rne(v[j] - bf16_up(hb));
        h[j] = (short)hb; l[j] = (short)lb;
    }
}

// ---------------- prep: split P (B layout) + Q (A-frag layout), y2/x2, out init ----
// Wave tasks: [0,8192) P-split+y2 | [8192,16384) Q-split | [16384,18432) x2 + out init.
__global__ __launch_bounds__(256) void vos_prep(
    const float* __restrict__ P, const float* __restrict__ Q,
    unsigned short* __restrict__ Pb, unsigned short* __restrict__ Qa,
    float* __restrict__ y2, float* __restrict__ x2, unsigned int* __restrict__ out)
{
    const int lane = threadIdx.x & 63;
    const int wid  = blockIdx.x * 4 + (threadIdx.x >> 6);

    if (wid < 8192) {
        // ---- P: wave = (row, col-pair); lane = (colhalf, s, cc). Writes are a
        // contiguous (permuted) 1 KB per wave; reads dense within 2x400B.
        const int row = wid >> 6;
        const int col = (wid & 63) * 2 + (lane >> 5);
        const int grp = lane & 31, s = grp >> 4, cc = grp & 15;
        const int pix = row * HW + col;
        const float* sp = P + (size_t)pix * NC;
        const int k0 = cc * 8;
        float4 a = {0.f,0.f,0.f,0.f}, b = {0.f,0.f,0.f,0.f};
        if (k0 <= 96)     a = *(const float4*)(sp + k0);       // k0..k0+3 (<100)
        if (k0 + 4 <= 96) b = *(const float4*)(sp + k0 + 4);   // cc<=11 only
        float v[8] = {a.x,a.y,a.z,a.w,b.x,b.y,b.z,b.w};
        short8 h, l; split8v(v, h, l);
        *(short8*)(Pb + (size_t)pix*256 + s*128 + ((cc ^ (col & 7)) << 3)) = s ? l : h;
        float part = 0.f;
#pragma unroll
        for (int j = 0; j < 8; ++j) part = fmaf(v[j], v[j], part);
        part += __shfl_xor(part, 1);  part += __shfl_xor(part, 2);
        part += __shfl_xor(part, 4);  part += __shfl_xor(part, 8);
        part += __shfl_xor(part, 16);                       // 32-lane group (s dup -> 2x)
        if (grp == 0) y2[pix] = 0.5f * part;
    } else if (wid < 16384) {
        // ---- Q: wave = (row, tile, s, kc); lane = (quad, n). Write = contiguous 1 KB.
        const int w2 = wid - 8192;
        const int row = w2 >> 6, rem = w2 & 63;
        const int tile = rem >> 3, s = (rem >> 2) & 1, kc = rem & 3;
        const int n = lane & 15, quad = lane >> 4;
        const int pix = row * HW + tile * 16 + n;
        const float* sp = Q + (size_t)pix * NC;
        const int k0 = (kc * 4 + quad) * 8;
        float4 a = {0.f,0.f,0.f,0.f}, b = {0.f,0.f,0.f,0.f};
        if (k0 <= 96)     a = *(const float4*)(sp + k0);
        if (k0 + 4 <= 96) b = *(const float4*)(sp + k0 + 4);
        float v[8] = {a.x,a.y,a.z,a.w,b.x,b.y,b.z,b.w};
        short8 h, l; split8v(v, h, l);
        *(short8*)(Qa + (((size_t)(row*8 + tile)*2 + s)*2048) + kc*512 + lane*8) = s ? l : h;
    } else {
        // ---- x2 per Q pixel (8 lanes/pixel) + out init to +inf
        const int w3 = wid - 16384;                         // 0..2047
        const int pix = w3 * 8 + (lane >> 3);
        const int lp = lane & 7;
        const float* sp = Q + (size_t)pix * NC;
        float part = 0.f;
#pragma unroll
        for (int c = 0; c < 4; ++c) {
            int k = lp * 16 + c * 4;
            if (k <= 96) {
                float4 t = *(const float4*)(sp + k);
                part = fmaf(t.x,t.x,part); part = fmaf(t.y,t.y,part);
                part = fmaf(t.z,t.z,part); part = fmaf(t.w,t.w,part);
            }
        }
        part += __shfl_xor(part, 1); part += __shfl_xor(part, 2); part += __shfl_xor(part, 4);
        if (lp == 0) x2[pix] = part;
        const int gid = w3 * 64 + lane;
        if (gid < HW * HW * NOBJ) out[gid] = 0x7F800000u;   // +inf bits
    }
}

// ---------------- main: banded MFMA GEMM + masked min epilogue ----------------
// Block: 256 thr (4 waves) = query rows {i0,i0+1} x 128 cols; wave w: cols [32w,32w+32).
// Grid: 64 stripes x 8 r-chunks (rows 5,5,4,4,4,4,4,4) = 512 blocks; atomicMin combine.
__global__ __launch_bounds__(256, 2) void vos_band(
    const unsigned short* __restrict__ Pb, const unsigned short* __restrict__ Qa,
    const int* __restrict__ labels, const int* __restrict__ gt,
    const float* __restrict__ y2, const float* __restrict__ x2,
    unsigned int* __restrict__ out)
{
    __shared__ unsigned short Bs[128 * 256];   // 64 KB: one P row, B layout, swizzled

    const int tid  = threadIdx.x;
    const int lane = tid & 63;
    const int wv   = tid >> 6;
    const int quad = lane >> 4;
    const int n    = lane & 15;
    const int j0w  = wv * 32;

    const int stripe = blockIdx.x >> 3;
    const int ck     = blockIdx.x & 7;
    const int i0     = stripe * 2;

    const int g0 = gt[0], g1 = gt[1], g2 = gt[2];

    // ---- A fragments: coalesced b128 loads from pre-split Qa (zero VALU)
    short8 Ah[2][2][4], Al[2][2][4];
#pragma unroll
    for (int uc = 0; uc < 2; ++uc)
#pragma unroll
    for (int ur = 0; ur < 2; ++ur) {
        const unsigned short* bse = Qa + (size_t)((i0 + ur) * 8 + wv * 2 + uc) * 4096;
#pragma unroll
        for (int kc = 0; kc < 4; ++kc) {
            Ah[uc][ur][kc] = *(const short8*)(bse + kc * 512 + lane * 8);
            Al[uc][ur][kc] = *(const short8*)(bse + 2048 + kc * 512 + lane * 8);
        }
    }
    float x2q[2][2][4];
#pragma unroll
    for (int uc = 0; uc < 2; ++uc)
#pragma unroll
    for (int ur = 0; ur < 2; ++ur)
#pragma unroll
    for (int reg = 0; reg < 4; ++reg)
        x2q[uc][ur][reg] = x2[(i0 + ur) * HW + j0w + 16 * uc + quad * 4 + reg];

    // Band masks for the triangular side tiles: offset = 16*du + n - m, valid |off|<=15.
    bool bgt[4], blt[4];
#pragma unroll
    for (int reg = 0; reg < 4; ++reg) {
        int m = quad * 4 + reg;
        bgt[reg] = n > m;   // du = -1
        blt[reg] = n < m;   // du = +1
    }

    float mm[2][2][4][NOBJ];
#pragma unroll
    for (int uc = 0; uc < 2; ++uc)
#pragma unroll
    for (int ur = 0; ur < 2; ++ur)
#pragma unroll
    for (int reg = 0; reg < 4; ++reg) {
        mm[uc][ur][reg][0] = BIGF; mm[uc][ur][reg][1] = BIGF; mm[uc][ur][reg][2] = BIGF;
    }

    // r-chunk: rows 5,5,4,4,4,4,4,4 covering [i0-15, i0+18]
    const int rbase = i0 - MD + ck * 4 + (ck < 2 ? ck : 2);
    const int rcnt  = (ck < 2) ? 5 : 4;
    const int rlo = max(rbase, 0);
    const int rhi = min(rbase + rcnt, HW);

    for (int r = rlo; r < rhi; ++r) {
        __syncthreads();                                   // prior iter's reads done
        {   // ---- async stage: Pb row r (64 KB, layout-identical) -> LDS; wave quarter
            const unsigned short* src = Pb + (size_t)r * 32768 + wv * 8192;
            unsigned short* dst = Bs + wv * 8192;
#pragma unroll
            for (int it = 0; it < 16; ++it) {
                __builtin_amdgcn_global_load_lds(
                    (const __attribute__((address_space(1))) unsigned int*)(src + it * 512 + lane * 8),
                    (__attribute__((address_space(3))) unsigned int*)(dst + it * 512),
                    16, 0, 0);
            }
        }
        __syncthreads();                                   // drains vmcnt then barrier

        const bool rv0 = (unsigned)(r - i0 + MD) <= 2u * MD;
        const bool rv1 = (unsigned)(r - i0 - 1 + MD) <= 2u * MD;
        const int  ry  = r * HW;

#pragma unroll
        for (int t = 0; t < 4; ++t) {
            const int base = j0w + 16 * (t - 1);
            if (base < 0 || base >= HW) continue;          // wave-uniform edge skip

            const int pcol = base + n;
            float y2v = y2[ry + pcol];
            int   lab = labels[ry + pcol];
            float pen0 = (lab == g0) ? y2v : BIGF;
            float pen1 = (lab == g1) ? y2v : BIGF;
            float pen2 = (lab == g2) ? y2v : BIGF;

            floatx4 C[2][2];
#pragma unroll
            for (int uc = 0; uc < 2; ++uc)
#pragma unroll
            for (int ur = 0; ur < 2; ++ur) C[uc][ur] = (floatx4){0.f, 0.f, 0.f, 0.f};

#pragma unroll
            for (int kc = 0; kc < 4; ++kc) {
                const int off = pcol * 256 + (((kc * 4 + quad) ^ (pcol & 7)) << 3);
                short8 bh = *(const short8*)(Bs + off);
                short8 bl = *(const short8*)(Bs + off + 128);
#pragma unroll
                for (int uc = 0; uc < 2; ++uc) {
                    if (uc == 0 && t == 3) continue;       // uc0 uses t in {0,1,2}
                    if (uc == 1 && t == 0) continue;       // uc1 uses t in {1,2,3}
#pragma unroll
                    for (int ur = 0; ur < 2; ++ur) {
                        C[uc][ur] = __builtin_amdgcn_mfma_f32_16x16x32_bf16(Ah[uc][ur][kc], bh, C[uc][ur], 0, 0, 0);
                        C[uc][ur] = __builtin_amdgcn_mfma_f32_16x16x32_bf16(Ah[uc][ur][kc], bl, C[uc][ur], 0, 0, 0);
                        C[uc][ur] = __builtin_amdgcn_mfma_f32_16x16x32_bf16(Al[uc][ur][kc], bh, C[uc][ur], 0, 0, 0);
                    }
                }
            }

            // ---- epilogue: d = x2 + y2 - 2*dot, masked per-object running min
#pragma unroll
            for (int uc = 0; uc < 2; ++uc) {
                if (uc == 0 && t == 3) continue;
                if (uc == 1 && t == 0) continue;
                const int du = t - 1 - uc;                 // -1, 0, +1 (compile-time)
#pragma unroll
                for (int ur = 0; ur < 2; ++ur) {
                    const bool rv = ur ? rv1 : rv0;
#pragma unroll
                    for (int reg = 0; reg < 4; ++reg) {
                        float tv = fmaf(C[uc][ur][reg], -2.f, x2q[uc][ur][reg]);
                        tv = rv ? tv : BIGF;
                        if (du == -1) tv = bgt[reg] ? tv : BIGF;
                        if (du == +1) tv = blt[reg] ? tv : BIGF;
                        mm[uc][ur][reg][0] = fminf(mm[uc][ur][reg][0], tv + pen0);
                        mm[uc][ur][reg][1] = fminf(mm[uc][ur][reg][1], tv + pen1);
                        mm[uc][ur][reg][2] = fminf(mm[uc][ur][reg][2], tv + pen2);
                    }
                }
            }
        }
    }

    // ---- min-reduce across the 16 N-lanes, then atomicMin combine (uint order ok, v>=0)
#pragma unroll
    for (int s = 1; s < 16; s <<= 1) {
#pragma unroll
        for (int uc = 0; uc < 2; ++uc)
#pragma unroll
        for (int ur = 0; ur < 2; ++ur)
#pragma unroll
        for (int reg = 0; reg < 4; ++reg)
#pragma unroll
        for (int o = 0; o < NOBJ; ++o)
            mm[uc][ur][reg][o] = fminf(mm[uc][ur][reg][o], __shfl_xor(mm[uc][ur][reg][o], s));
    }
    if (n == 0) {
#pragma unroll
        for (int uc = 0; uc < 2; ++uc)
#pragma unroll
        for (int ur = 0; ur < 2; ++ur)
#pragma unroll
        for (int reg = 0; reg < 4; ++reg) {
            const int qrow = i0 + ur;
            const int qcol = j0w + 16 * uc + quad * 4 + reg;
            unsigned int* op = out + ((size_t)(qrow * HW + qcol)) * NOBJ;
#pragma unroll
            for (int o = 0; o < NOBJ; ++o) {
                float v = fminf(fmaxf(mm[uc][ur][reg][o], 0.f), 1.0f);  // 1.0 = mask padding
                atomicMin(op + o, __float_as_uint(v));
            }
        }
    }
}

extern "C" void kernel_launch(void* const* d_in, const int* in_sizes, int n_in,
                              void* d_out, int out_size, void* d_ws, size_t ws_size,
                              hipStream_t stream) {
    const float* P      = (const float*)d_in[0];   // prev_frame_embedding [128,128,100]
    const float* Q      = (const float*)d_in[1];   // query_embedding      [128,128,100]
    const int*   labels = (const int*)d_in[2];     // prev_frame_labels    [128,128,1]
    const int*   gt     = (const int*)d_in[3];     // gt_ids [3]
    // d_in[4] = max_distance (always 15; compiled for MD=15)

    // Workspace layout (16,908,288 B total):
    float* y2 = (float*)d_ws;                                   //  64 KB
    float* x2 = y2 + HW * HW;                                   //  64 KB
    unsigned short* Pb = (unsigned short*)(x2 + HW * HW);       // 8.39 MB
    unsigned short* Qa = Pb + (size_t)HW * HW * 256;            // 8.39 MB
    unsigned int* out = (unsigned int*)d_out;

    vos_prep<<<4608, 256, 0, stream>>>(P, Q, Pb, Qa, y2, x2, out);
    vos_band<<<64 * 8, 256, 0, stream>>>(Pb, Qa, labels, gt, y2, x2, out);
}

// Round 4
// 112.785 us; speedup vs baseline: 2.2055x; 1.0734x over previous
//
#include <hip/hip_runtime.h>
#include <cstdint>

// Local NN VOS features via banded bf16-split MFMA GEMM. MI355X round 4.
//
// Round-4 changes vs round 3 (which was staging-bound: FETCH 98 MB, Mfma 12.5%,
// phase-alternating barrier structure -> all pipes ~50% duty):
//   1. Cross-iteration double-buffered staging: DMA for row r+1 issued at top of
//      step r -> the vmcnt(0)+barrier drain is cheap (load had ~2800 cyc in flight).
//   2. 8-row chunks (256 blocks) + XCD-grouped block mapping (b&7 = XCD, 8
//      contiguous stripes per XCD) -> per-XCD Pb working set ~2.9 MB < 4 MiB L2.
//   3. labels/y2 staged to LDS once per block (no global latency in inner loop).
// Numerics unchanged: bf16 hi/lo split, 3-MFMA scheme (fp16-single-B fails error
// analysis: 10 mantissa bits -> ~5.6e-3 sigma vs 2e-2 absmax threshold).
//
// Workspace requirement: 16.2 MB (y2 64K + x2 64K + Pb 8.39M + Qa 8.39M).

#define HW   128
#define NC   100
#define MD   15
#define NOBJ 3
#define BIGF 1e30f

typedef __attribute__((ext_vector_type(8))) short  short8;   // 8 x bf16 (4 VGPR)
typedef __attribute__((ext_vector_type(4))) float  floatx4;  // MFMA C/D

__device__ inline unsigned short bf16_rne(float x) {
    union { float f; unsigned u; } v; v.f = x;
    unsigned r = v.u + 0x7FFFu + ((v.u >> 16) & 1u);
    return (unsigned short)(r >> 16);
}
__device__ inline float bf16_up(unsigned short h) {
    union { unsigned u; float f; } v; v.u = ((unsigned)h) << 16; return v.f;
}
__device__ inline void split8v(const float* v, short8& h, short8& l) {
#pragma unroll
    for (int j = 0; j < 8; ++j) {
        unsigned short hb = bf16_rne(v[j]);
        unsigned short lb = bf16_rne(v[j] - bf16_up(hb));
        h[j] = (short)hb; l[j] = (short)lb;
    }
}

// ---------------- prep: split P (B layout) + Q (A-frag layout), y2/x2, out init ----
__global__ __launch_bounds__(256) void vos_prep(
    const float* __restrict__ P, const float* __restrict__ Q,
    unsigned short* __restrict__ Pb, unsigned short* __restrict__ Qa,
    float* __restrict__ y2, float* __restrict__ x2, unsigned int* __restrict__ out)
{
    const int lane = threadIdx.x & 63;
    const int wid  = blockIdx.x * 4 + (threadIdx.x >> 6);

    if (wid < 8192) {
        // ---- P: wave = (row, col-pair); lane = (colhalf, s, cc).
        const int row = wid >> 6;
        const int col = (wid & 63) * 2 + (lane >> 5);
        const int grp = lane & 31, s = grp >> 4, cc = grp & 15;
        const int pix = row * HW + col;
        const float* sp = P + (size_t)pix * NC;
        const int k0 = cc * 8;
        float4 a = {0.f,0.f,0.f,0.f}, b = {0.f,0.f,0.f,0.f};
        if (k0 <= 96)     a = *(const float4*)(sp + k0);
        if (k0 + 4 <= 96) b = *(const float4*)(sp + k0 + 4);
        float v[8] = {a.x,a.y,a.z,a.w,b.x,b.y,b.z,b.w};
        short8 h, l; split8v(v, h, l);
        *(short8*)(Pb + (size_t)pix*256 + s*128 + ((cc ^ (col & 7)) << 3)) = s ? l : h;
        float part = 0.f;
#pragma unroll
        for (int j = 0; j < 8; ++j) part = fmaf(v[j], v[j], part);
        part += __shfl_xor(part, 1);  part += __shfl_xor(part, 2);
        part += __shfl_xor(part, 4);  part += __shfl_xor(part, 8);
        part += __shfl_xor(part, 16);
        if (grp == 0) y2[pix] = 0.5f * part;
    } else if (wid < 16384) {
        // ---- Q: wave = (row, tile, s, kc); lane = (quad, n).
        const int w2 = wid - 8192;
        const int row = w2 >> 6, rem = w2 & 63;
        const int tile = rem >> 3, s = (rem >> 2) & 1, kc = rem & 3;
        const int nn = lane & 15, quad = lane >> 4;
        const int pix = row * HW + tile * 16 + nn;
        const float* sp = Q + (size_t)pix * NC;
        const int k0 = (kc * 4 + quad) * 8;
        float4 a = {0.f,0.f,0.f,0.f}, b = {0.f,0.f,0.f,0.f};
        if (k0 <= 96)     a = *(const float4*)(sp + k0);
        if (k0 + 4 <= 96) b = *(const float4*)(sp + k0 + 4);
        float v[8] = {a.x,a.y,a.z,a.w,b.x,b.y,b.z,b.w};
        short8 h, l; split8v(v, h, l);
        *(short8*)(Qa + (((size_t)(row*8 + tile)*2 + s)*2048) + kc*512 + lane*8) = s ? l : h;
    } else {
        // ---- x2 per Q pixel + out init to +inf
        const int w3 = wid - 16384;
        const int pix = w3 * 8 + (lane >> 3);
        const int lp = lane & 7;
        const float* sp = Q + (size_t)pix * NC;
        float part = 0.f;
#pragma unroll
        for (int c = 0; c < 4; ++c) {
            int k = lp * 16 + c * 4;
            if (k <= 96) {
                float4 t = *(const float4*)(sp + k);
                part = fmaf(t.x,t.x,part); part = fmaf(t.y,t.y,part);
                part = fmaf(t.z,t.z,part); part = fmaf(t.w,t.w,part);
            }
        }
        part += __shfl_xor(part, 1); part += __shfl_xor(part, 2); part += __shfl_xor(part, 4);
        if (lp == 0) x2[pix] = part;
        const int gid = w3 * 64 + lane;
        if (gid < HW * HW * NOBJ) out[gid] = 0x7F800000u;
    }
}

// ---------------- main: banded MFMA GEMM, double-buffered, XCD-grouped ----------
// Block: 256 thr (4 waves) = query rows {i0,i0+1} x 128 cols; wave w: cols [32w,32w+32).
// Grid: 256 blocks = 8 XCD-groups x 8 stripes x 4 row-chunks (8 rows each).
__global__ __launch_bounds__(256, 1) void vos_band(
    const unsigned short* __restrict__ Pb, const unsigned short* __restrict__ Qa,
    const int* __restrict__ labels, const int* __restrict__ gt,
    const float* __restrict__ y2, const float* __restrict__ x2,
    unsigned int* __restrict__ out)
{
    __shared__ unsigned short Bs[2][128 * 256];   // 2 x 64 KB double buffer
    __shared__ int   lab_s[8 * 128];
    __shared__ float y2_s[8 * 128];

    const int tid  = threadIdx.x;
    const int lane = tid & 63;
    const int wv   = tid >> 6;
    const int quad = lane >> 4;
    const int n    = lane & 15;
    const int j0w  = wv * 32;

    // XCD-grouped mapping: b&7 selects XCD (round-robin dispatch heuristic);
    // 8 contiguous stripes per XCD -> Pb rows [16x-15,16x+30] (~2.9 MB) stay L2-hot.
    const int b      = blockIdx.x;
    const int xcd    = b & 7;
    const int wi     = b >> 3;               // 0..31
    const int stripe = xcd * 8 + (wi & 7);   // 0..63
    const int ck     = wi >> 3;              // 0..3
    const int i0     = stripe * 2;
    const int rb     = i0 - MD + ck * 8;     // rows [i0-15, i0+16] in 4 chunks of 8
    const int rlo    = max(rb, 0);
    const int rhi    = min(rb + 8, HW);

    const int g0 = gt[0], g1 = gt[1], g2 = gt[2];

    // ---- kick off DMA of the first row before any other work
    if (rlo < rhi) {
        const unsigned short* src = Pb + (size_t)rlo * 32768 + wv * 8192;
        unsigned short* dst = &Bs[rlo & 1][wv * 8192];
#pragma unroll
        for (int it = 0; it < 16; ++it)
            __builtin_amdgcn_global_load_lds(
                (const __attribute__((address_space(1))) unsigned int*)(src + it * 512 + lane * 8),
                (__attribute__((address_space(3))) unsigned int*)(dst + it * 512), 16, 0, 0);
    }

    // ---- stage labels/y2 for the chunk's rows into LDS (poison in unused slots is never read)
    for (int t = tid; t < 8 * 128; t += 256) {
        int rr = t >> 7, c = t & 127, r = rb + rr;
        if ((unsigned)r < (unsigned)HW) {
            lab_s[t] = labels[r * HW + c];
            y2_s[t]  = y2[r * HW + c];
        }
    }

    // ---- A fragments: coalesced b128 loads from pre-split Qa
    short8 Ah[2][2][4], Al[2][2][4];
#pragma unroll
    for (int uc = 0; uc < 2; ++uc)
#pragma unroll
    for (int ur = 0; ur < 2; ++ur) {
        const unsigned short* bse = Qa + (size_t)((i0 + ur) * 8 + wv * 2 + uc) * 4096;
#pragma unroll
        for (int kc = 0; kc < 4; ++kc) {
            Ah[uc][ur][kc] = *(const short8*)(bse + kc * 512 + lane * 8);
            Al[uc][ur][kc] = *(const short8*)(bse + 2048 + kc * 512 + lane * 8);
        }
    }
    float x2q[2][2][4];
#pragma unroll
    for (int uc = 0; uc < 2; ++uc)
#pragma unroll
    for (int ur = 0; ur < 2; ++ur)
#pragma unroll
    for (int reg = 0; reg < 4; ++reg)
        x2q[uc][ur][reg] = x2[(i0 + ur) * HW + j0w + 16 * uc + quad * 4 + reg];

    // Band masks for the triangular side tiles: offset = 16*du + n - m, valid |off|<=15.
    bool bgt[4], blt[4];
#pragma unroll
    for (int reg = 0; reg < 4; ++reg) {
        int m = quad * 4 + reg;
        bgt[reg] = n > m;   // du = -1
        blt[reg] = n < m;   // du = +1
    }

    float mm[2][2][4][NOBJ];
#pragma unroll
    for (int uc = 0; uc < 2; ++uc)
#pragma unroll
    for (int ur = 0; ur < 2; ++ur)
#pragma unroll
    for (int reg = 0; reg < 4; ++reg) {
        mm[uc][ur][reg][0] = BIGF; mm[uc][ur][reg][1] = BIGF; mm[uc][ur][reg][2] = BIGF;
    }

    __syncthreads();   // lab/y2 visible; each wave's own row-rlo DMA drained (vmcnt 0)

    for (int r = rlo; r < rhi; ++r) {
        // ---- prefetch next row into the other buffer; consumed after next barrier,
        // so the end-of-loop vmcnt drain overlaps this whole iteration's compute.
        if (r + 1 < rhi) {
            const unsigned short* src = Pb + (size_t)(r + 1) * 32768 + wv * 8192;
            unsigned short* dst = &Bs[(r + 1) & 1][wv * 8192];
#pragma unroll
            for (int it = 0; it < 16; ++it)
                __builtin_amdgcn_global_load_lds(
                    (const __attribute__((address_space(1))) unsigned int*)(src + it * 512 + lane * 8),
                    (__attribute__((address_space(3))) unsigned int*)(dst + it * 512), 16, 0, 0);
        }

        const unsigned short* Bcur = &Bs[r & 1][0];
        const bool rv0 = (unsigned)(r - i0 + MD) <= 2u * MD;
        const bool rv1 = (unsigned)(r - i0 - 1 + MD) <= 2u * MD;
        const int  rr8 = (r - rb) * 128;

#pragma unroll
        for (int t = 0; t < 4; ++t) {
            const int base = j0w + 16 * (t - 1);
            if (base < 0 || base >= HW) continue;          // wave-uniform edge skip

            const int pcol = base + n;
            float y2v = y2_s[rr8 + pcol];
            int   lab = lab_s[rr8 + pcol];
            float pen0 = (lab == g0) ? y2v : BIGF;
            float pen1 = (lab == g1) ? y2v : BIGF;
            float pen2 = (lab == g2) ? y2v : BIGF;

            floatx4 C[2][2];
#pragma unroll
            for (int uc = 0; uc < 2; ++uc)
#pragma unroll
            for (int ur = 0; ur < 2; ++ur) C[uc][ur] = (floatx4){0.f, 0.f, 0.f, 0.f};

#pragma unroll
            for (int kc = 0; kc < 4; ++kc) {
                const int off = pcol * 256 + (((kc * 4 + quad) ^ (pcol & 7)) << 3);
                short8 bh = *(const short8*)(Bcur + off);
                short8 bl = *(const short8*)(Bcur + off + 128);
#pragma unroll
                for (int uc = 0; uc < 2; ++uc) {
                    if (uc == 0 && t == 3) continue;       // uc0 uses t in {0,1,2}
                    if (uc == 1 && t == 0) continue;       // uc1 uses t in {1,2,3}
#pragma unroll
                    for (int ur = 0; ur < 2; ++ur) {
                        C[uc][ur] = __builtin_amdgcn_mfma_f32_16x16x32_bf16(Ah[uc][ur][kc], bh, C[uc][ur], 0, 0, 0);
                        C[uc][ur] = __builtin_amdgcn_mfma_f32_16x16x32_bf16(Ah[uc][ur][kc], bl, C[uc][ur], 0, 0, 0);
                        C[uc][ur] = __builtin_amdgcn_mfma_f32_16x16x32_bf16(Al[uc][ur][kc], bh, C[uc][ur], 0, 0, 0);
                    }
                }
            }

            // ---- epilogue: d = x2 + y2 - 2*dot, masked per-object running min
#pragma unroll
            for (int uc = 0; uc < 2; ++uc) {
                if (uc == 0 && t == 3) continue;
                if (uc == 1 && t == 0) continue;
                const int du = t - 1 - uc;                 // -1, 0, +1 (compile-time)
#pragma unroll
                for (int ur = 0; ur < 2; ++ur) {
                    const bool rv = ur ? rv1 : rv0;
#pragma unroll
                    for (int reg = 0; reg < 4; ++reg) {
                        float tv = fmaf(C[uc][ur][reg], -2.f, x2q[uc][ur][reg]);
                        tv = rv ? tv : BIGF;
                        if (du == -1) tv = bgt[reg] ? tv : BIGF;
                        if (du == +1) tv = blt[reg] ? tv : BIGF;
                        mm[uc][ur][reg][0] = fminf(mm[uc][ur][reg][0], tv + pen0);
                        mm[uc][ur][reg][1] = fminf(mm[uc][ur][reg][1], tv + pen1);
                        mm[uc][ur][reg][2] = fminf(mm[uc][ur][reg][2], tv + pen2);
                    }
                }
            }
        }
        __syncthreads();   // drains this iter's prefetch DMA (had full compute in flight)
    }

    // ---- min-reduce across the 16 N-lanes, then atomicMin combine (uint order ok, v>=0)
#pragma unroll
    for (int s = 1; s < 16; s <<= 1) {
#pragma unroll
        for (int uc = 0; uc < 2; ++uc)
#pragma unroll
        for (int ur = 0; ur < 2; ++ur)
#pragma unroll
        for (int reg = 0; reg < 4; ++reg)
#pragma unroll
        for (int o = 0; o < NOBJ; ++o)
            mm[uc][ur][reg][o] = fminf(mm[uc][ur][reg][o], __shfl_xor(mm[uc][ur][reg][o], s));
    }
    if (n == 0) {
#pragma unroll
        for (int uc = 0; uc < 2; ++uc)
#pragma unroll
        for (int ur = 0; ur < 2; ++ur)
#pragma unroll
        for (int reg = 0; reg < 4; ++reg) {
            const int qrow = i0 + ur;
            const int qcol = j0w + 16 * uc + quad * 4 + reg;
            unsigned int* op = out + ((size_t)(qrow * HW + qcol)) * NOBJ;
#pragma unroll
            for (int o = 0; o < NOBJ; ++o) {
                float v = fminf(fmaxf(mm[uc][ur][reg][o], 0.f), 1.0f);  // 1.0 = mask padding
                atomicMin(op + o, __float_as_uint(v));
            }
        }
    }
}

extern "C" void kernel_launch(void* const* d_in, const int* in_sizes, int n_in,
                              void* d_out, int out_size, void* d_ws, size_t ws_size,
                              hipStream_t stream) {
    const float* P      = (const float*)d_in[0];   // prev_frame_embedding [128,128,100]
    const float* Q      = (const float*)d_in[1];   // query_embedding      [128,128,100]
    const int*   labels = (const int*)d_in[2];     // prev_frame_labels    [128,128,1]
    const int*   gt     = (const int*)d_in[3];     // gt_ids [3]
    // d_in[4] = max_distance (always 15; compiled for MD=15)

    // Workspace layout (16,908,288 B total):
    float* y2 = (float*)d_ws;                                   //  64 KB
    float* x2 = y2 + HW * HW;                                   //  64 KB
    unsigned short* Pb = (unsigned short*)(x2 + HW * HW);       // 8.39 MB
    unsigned short* Qa = Pb + (size_t)HW * HW * 256;            // 8.39 MB
    unsigned int* out = (unsigned int*)d_out;

    vos_prep<<<4608, 256, 0, stream>>>(P, Q, Pb, Qa, y2, x2, out);
    vos_band<<<256, 256, 0, stream>>>(Pb, Qa, labels, gt, y2, x2, out);
}

// Round 5
// 102.798 us; speedup vs baseline: 2.4197x; 1.0972x over previous
//
#include <hip/hip_runtime.h>
#include <cstdint>

// Local NN VOS features via banded EXACT i16-fixed-point i8-MFMA GEMM. MI355X round 5.
//
// d(i,j,o) = min over |dy|<=15,|dx|<=15 of (in-frame && label==gt[o] ? ||Q-P||^2 : 1.0)
//          = clamp( min_valid( x2 + y2 - 2 Q.P ), 0, 1.0 )
//
// Round-5 engine swap (was bf16 hi/lo, 3 MFMA, 64 KB/row LDS):
//   q ~ (h*256+l)/4096, h,l in i8 (exact i16 fixed point; quantization sigma ~1e-4/elem).
//   dot*2^24 = 65536*S_hh + 256*S_(hl+lh) + S_ll, all EXACT via mfma_i32_16x16x64_i8
//   (planes bounded: hh<=8.2e5, mid<=4.3e6, ll<=2.1e6 -- no i32 overflow, fp32-exact cvt).
//   -> LDS row image 32 KB (was 64) -> double-buffer + 2 blocks/CU (8 waves, m114 overlap)
//   -> staged bytes halve (Pq 4.2 MB total; 1.5 MB per XCD group)
//   -> 8 MFMA/unit (was 12).
// Epilogue/masking/atomicMin structure unchanged from the verified round-2/3/4 kernels.
//
// Workspace: y2 64K + x2 64K + Pq 4.19M + Qa 4.19M ~= 8.5 MB.

#define HW   128
#define NC   100
#define MD   15
#define NOBJ 3
#define BIGF 1e30f

typedef __attribute__((ext_vector_type(4))) int   intx4;   // 16 i8 / 4 i32 (MFMA A/B/C)
typedef __attribute__((ext_vector_type(4))) float floatx4;

// q_int = rne(x*4096) clamped; h = (q_int+128)>>8 in [-127,127]; l = q_int - h*256 in [-128,127]
__device__ inline void quant16(const float* v, signed char* h, signed char* l) {
#pragma unroll
    for (int j = 0; j < 16; ++j) {
        int qi = __float2int_rn(v[j] * 4096.f);
        qi = max(-32512, min(32512, qi));
        int hh = (qi + 128) >> 8;
        int ll = qi - (hh << 8);
        h[j] = (signed char)hh; l[j] = (signed char)ll;
    }
}
__device__ inline intx4 pack16(const signed char* b) {
    intx4 r;
#pragma unroll
    for (int w = 0; w < 4; ++w)
        r[w] = (b[4*w] & 255) | ((b[4*w+1] & 255) << 8) |
               ((b[4*w+2] & 255) << 16) | ((b[4*w+3] & 255) << 24);
    return r;
}

// ---------------- prep: quantize P (B layout) + Q (A-frag layout), y2/x2, out init ----
// Waves: [0,4096) P | [4096,8192) Q | [8192,10240) x2 + out init.  Grid 2560 x 256.
__global__ __launch_bounds__(256) void vos_prep(
    const float* __restrict__ P, const float* __restrict__ Q,
    signed char* __restrict__ Pq, signed char* __restrict__ Qa,
    float* __restrict__ y2, float* __restrict__ x2, unsigned int* __restrict__ out)
{
    const int lane = threadIdx.x & 63;
    const int wid  = blockIdx.x * 4 + (threadIdx.x >> 6);

    if (wid < 4096) {
        // ---- P: wave = 4 pixels; lane = (pix4, chunk c): s=c>>3 plane, cr=c&7 -> k=cr*16..+15
        const int pix = wid * 4 + (lane >> 4);
        const int col = pix & 127;
        const int c = lane & 15, s = c >> 3, cr = c & 7;
        const float* sp = P + (size_t)pix * NC;
        const int k0 = cr * 16;
        float v[16];
#pragma unroll
        for (int c4 = 0; c4 < 4; ++c4) {
            float4 a = {0.f,0.f,0.f,0.f};
            if (k0 + c4 * 4 + 4 <= NC) a = *(const float4*)(sp + k0 + c4 * 4);
            v[c4*4+0]=a.x; v[c4*4+1]=a.y; v[c4*4+2]=a.z; v[c4*4+3]=a.w;
        }
        signed char hb[16], lb[16]; quant16(v, hb, lb);
        // B-image: pixel block 256 B = [s:2][chunk^(col&7):8][16 i8]
        *(intx4*)(Pq + (size_t)pix * 256 + s * 128 + ((cr ^ (col & 7)) << 4)) =
            pack16(s ? lb : hb);
        float part = 0.f;
#pragma unroll
        for (int j = 0; j < 16; ++j) part = fmaf(v[j], v[j], part);
        part += __shfl_xor(part, 1); part += __shfl_xor(part, 2);
        part += __shfl_xor(part, 4); part += __shfl_xor(part, 8);
        if ((lane & 15) == 0) y2[pix] = 0.5f * part;   // both s-halves summed -> 2x
    } else if (wid < 8192) {
        // ---- Q: wave = (row, tile, s, kh); lane = (quad, m): k = kh*64 + quad*16 + j
        const int w2 = wid - 4096;
        const int row = w2 >> 5, rem = w2 & 31;
        const int tile = rem >> 2, s = (rem >> 1) & 1, kh = rem & 1;
        const int m = lane & 15, quad = lane >> 4;
        const int pix = row * HW + tile * 16 + m;
        const float* sp = Q + (size_t)pix * NC;
        const int k0 = kh * 64 + quad * 16;
        float v[16];
#pragma unroll
        for (int c4 = 0; c4 < 4; ++c4) {
            float4 a = {0.f,0.f,0.f,0.f};
            if (k0 + c4 * 4 + 4 <= NC) a = *(const float4*)(sp + k0 + c4 * 4);
            v[c4*4+0]=a.x; v[c4*4+1]=a.y; v[c4*4+2]=a.z; v[c4*4+3]=a.w;
        }
        signed char hb[16], lb[16]; quant16(v, hb, lb);
        // A-frag image: [row][tile][s][kh] -> 1 KB frags, lane-contiguous
        *(intx4*)(Qa + ((size_t)(((row*8 + tile)*2 + s)*2 + kh))*1024 + lane*16) =
            pack16(s ? lb : hb);
    } else {
        // ---- x2 per Q pixel (8 lanes/pixel) + out init to +inf
        const int w3 = wid - 8192;                      // 0..2047
        const int pix = w3 * 8 + (lane >> 3);
        const int lp = lane & 7;
        const float* sp = Q + (size_t)pix * NC;
        float part = 0.f;
#pragma unroll
        for (int cc = 0; cc < 4; ++cc) {
            int k = lp * 16 + cc * 4;
            if (k <= 96) {
                float4 t = *(const float4*)(sp + k);
                part = fmaf(t.x,t.x,part); part = fmaf(t.y,t.y,part);
                part = fmaf(t.z,t.z,part); part = fmaf(t.w,t.w,part);
            }
        }
        part += __shfl_xor(part, 1); part += __shfl_xor(part, 2); part += __shfl_xor(part, 4);
        if (lp == 0) x2[pix] = part;
        const int gid = w3 * 64 + lane;
        if (gid < HW * HW * NOBJ) out[gid] = 0x7F800000u;
    }
}

// ---------------- main: banded i8-MFMA GEMM, double-buffered, 2 blocks/CU -----------
// Block: 256 thr (4 waves) = query rows {i0,i0+1} x 128 cols; wave w: cols [32w,32w+32).
// Grid: 512 = 8 XCD-groups x 8 stripes x 8 r-chunks (rows 5,5,4,4,4,4,4,4 over the 34-row band).
__global__ __launch_bounds__(256, 2) void vos_band(
    const signed char* __restrict__ Pq, const signed char* __restrict__ Qa,
    const int* __restrict__ labels, const int* __restrict__ gt,
    const float* __restrict__ y2, const float* __restrict__ x2,
    unsigned int* __restrict__ out)
{
    __shared__ signed char Bs[2][32768];     // 2 x 32 KB double buffer (one P row each)
    __shared__ int   lab_s[5 * 128];
    __shared__ float y2_s[5 * 128];

    const int tid  = threadIdx.x;
    const int lane = tid & 63;
    const int wv   = tid >> 6;
    const int quad = lane >> 4;
    const int n    = lane & 15;
    const int j0w  = wv * 32;

    // XCD grouping: b&7 = XCD (round-robin heuristic); 8 contiguous stripes/XCD
    // -> per-XCD Pq footprint 46 rows x 32 KB = 1.5 MB << 4 MiB L2.
    const int b      = blockIdx.x;
    const int xcd    = b & 7;
    const int wi     = b >> 3;               // 0..63
    const int stripe = xcd * 8 + (wi & 7);   // 0..63
    const int ck     = wi >> 3;              // 0..7
    const int i0     = stripe * 2;
    const int rbase  = i0 - MD + ck * 4 + (ck < 2 ? ck : 2);   // 5,5,4,4,4,4,4,4
    const int rcnt   = (ck < 2) ? 5 : 4;
    const int rlo    = max(rbase, 0);
    const int rhi    = min(rbase + rcnt, HW);

    const int g0 = gt[0], g1 = gt[1], g2 = gt[2];

    // ---- kick off DMA of the first row immediately (32 KB; 8 x 16B-wide per wave)
    if (rlo < rhi) {
        const signed char* src = Pq + (size_t)rlo * 32768 + wv * 8192;
        signed char* dst = &Bs[rlo & 1][wv * 8192];
#pragma unroll
        for (int it = 0; it < 8; ++it)
            __builtin_amdgcn_global_load_lds(
                (const __attribute__((address_space(1))) unsigned int*)(src + it * 1024 + lane * 16),
                (__attribute__((address_space(3))) unsigned int*)(dst + it * 1024), 16, 0, 0);
    }

    // ---- stage labels/y2 for the chunk rows
    for (int t = tid; t < 5 * 128; t += 256) {
        int rr = t >> 7, c = t & 127, r = rbase + rr;
        if (rr < rcnt && (unsigned)r < (unsigned)HW) {
            lab_s[t] = labels[r * HW + c];
            y2_s[t]  = y2[r * HW + c];
        }
    }

    // ---- A fragments from pre-quantized Qa (coalesced b128, zero VALU)
    intx4 Ah[2][2][2], Al[2][2][2];          // [uc][ur][kh]
#pragma unroll
    for (int uc = 0; uc < 2; ++uc)
#pragma unroll
    for (int ur = 0; ur < 2; ++ur) {
        const signed char* bse = Qa + (size_t)((i0 + ur) * 8 + wv * 2 + uc) * 4096;
#pragma unroll
        for (int kh = 0; kh < 2; ++kh) {
            Ah[uc][ur][kh] = *(const intx4*)(bse + kh * 1024 + lane * 16);          // s=0
            Al[uc][ur][kh] = *(const intx4*)(bse + 2048 + kh * 1024 + lane * 16);   // s=1
        }
    }
    float x2q[2][2][4];
#pragma unroll
    for (int uc = 0; uc < 2; ++uc)
#pragma unroll
    for (int ur = 0; ur < 2; ++ur)
#pragma unroll
    for (int reg = 0; reg < 4; ++reg)
        x2q[uc][ur][reg] = x2[(i0 + ur) * HW + j0w + 16 * uc + quad * 4 + reg];

    // Band masks for triangular side tiles: offset = 16*du + n - m, valid |off|<=15.
    bool bgt[4], blt[4];
#pragma unroll
    for (int reg = 0; reg < 4; ++reg) {
        int m = quad * 4 + reg;
        bgt[reg] = n > m;   // du = -1
        blt[reg] = n < m;   // du = +1
    }

    float mm[2][2][4][NOBJ];
#pragma unroll
    for (int uc = 0; uc < 2; ++uc)
#pragma unroll
    for (int ur = 0; ur < 2; ++ur)
#pragma unroll
    for (int reg = 0; reg < 4; ++reg) {
        mm[uc][ur][reg][0] = BIGF; mm[uc][ur][reg][1] = BIGF; mm[uc][ur][reg][2] = BIGF;
    }

    __syncthreads();   // lab/y2 visible; first-row DMA drained (each wave waits own vmcnt)

    for (int r = rlo; r < rhi; ++r) {
        // ---- prefetch next row into the other buffer (drained at end-of-iter barrier,
        // with this whole iteration's compute in flight behind it)
        if (r + 1 < rhi) {
            const signed char* src = Pq + (size_t)(r + 1) * 32768 + wv * 8192;
            signed char* dst = &Bs[(r + 1) & 1][wv * 8192];
#pragma unroll
            for (int it = 0; it < 8; ++it)
                __builtin_amdgcn_global_load_lds(
                    (const __attribute__((address_space(1))) unsigned int*)(src + it * 1024 + lane * 16),
                    (__attribute__((address_space(3))) unsigned int*)(dst + it * 1024), 16, 0, 0);
        }

        const signed char* Bcur = &Bs[r & 1][0];
        const bool rv0 = (unsigned)(r - i0 + MD) <= 2u * MD;
        const bool rv1 = (unsigned)(r - i0 - 1 + MD) <= 2u * MD;
        const int  rr8 = (r - rbase) * 128;

#pragma unroll
        for (int t = 0; t < 4; ++t) {
            const int base = j0w + 16 * (t - 1);
            if (base < 0 || base >= HW) continue;      // wave-uniform edge skip

            const int pcol = base + n;
            float y2v = y2_s[rr8 + pcol];
            int   lab = lab_s[rr8 + pcol];
            float pen0 = (lab == g0) ? y2v : BIGF;
            float pen1 = (lab == g1) ? y2v : BIGF;
            float pen2 = (lab == g2) ? y2v : BIGF;

            intx4 Chh[2][2], Cm[2][2], Cll[2][2];
#pragma unroll
            for (int uc = 0; uc < 2; ++uc)
#pragma unroll
            for (int ur = 0; ur < 2; ++ur) {
                Chh[uc][ur] = (intx4){0,0,0,0};
                Cm[uc][ur]  = (intx4){0,0,0,0};
                Cll[uc][ur] = (intx4){0,0,0,0};
            }

#pragma unroll
            for (int kh = 0; kh < 2; ++kh) {
                const int off = pcol * 256 + (((kh * 4 + quad) ^ (pcol & 7)) << 4);
                intx4 bh = *(const intx4*)(Bcur + off);
                intx4 bl = *(const intx4*)(Bcur + off + 128);
#pragma unroll
                for (int uc = 0; uc < 2; ++uc) {
                    if (uc == 0 && t == 3) continue;   // uc0 uses t in {0,1,2}
                    if (uc == 1 && t == 0) continue;   // uc1 uses t in {1,2,3}
#pragma unroll
                    for (int ur = 0; ur < 2; ++ur) {
                        Chh[uc][ur] = __builtin_amdgcn_mfma_i32_16x16x64_i8(Ah[uc][ur][kh], bh, Chh[uc][ur], 0, 0, 0);
                        Cm [uc][ur] = __builtin_amdgcn_mfma_i32_16x16x64_i8(Ah[uc][ur][kh], bl, Cm [uc][ur], 0, 0, 0);
                        Cm [uc][ur] = __builtin_amdgcn_mfma_i32_16x16x64_i8(Al[uc][ur][kh], bh, Cm [uc][ur], 0, 0, 0);
                        Cll[uc][ur] = __builtin_amdgcn_mfma_i32_16x16x64_i8(Al[uc][ur][kh], bl, Cll[uc][ur], 0, 0, 0);
                    }
                }
            }

            // ---- epilogue: 2*dot = hh*2^-7 + mid*2^-15 + ll*2^-23 (exact cvt, planes < 2^24)
#pragma unroll
            for (int uc = 0; uc < 2; ++uc) {
                if (uc == 0 && t == 3) continue;
                if (uc == 1 && t == 0) continue;
                const int du = t - 1 - uc;             // -1, 0, +1 (compile-time)
#pragma unroll
                for (int ur = 0; ur < 2; ++ur) {
                    const bool rv = ur ? rv1 : rv0;
#pragma unroll
                    for (int reg = 0; reg < 4; ++reg) {
                        float g = fmaf((float)Chh[uc][ur][reg], 0.0078125f,
                                  fmaf((float)Cm[uc][ur][reg], 3.0517578125e-05f,
                                       (float)Cll[uc][ur][reg] * 1.1920928955078125e-07f));
                        float tv = x2q[uc][ur][reg] - g;
                        tv = rv ? tv : BIGF;
                        if (du == -1) tv = bgt[reg] ? tv : BIGF;
                        if (du == +1) tv = blt[reg] ? tv : BIGF;
                        mm[uc][ur][reg][0] = fminf(mm[uc][ur][reg][0], tv + pen0);
                        mm[uc][ur][reg][1] = fminf(mm[uc][ur][reg][1], tv + pen1);
                        mm[uc][ur][reg][2] = fminf(mm[uc][ur][reg][2], tv + pen2);
                    }
                }
            }
        }
        __syncthreads();   // drains prefetch DMA; next iter reads the other buffer
    }

    // ---- min-reduce across the 16 N-lanes, then atomicMin combine (uint order ok, v>=0)
#pragma unroll
    for (int s = 1; s < 16; s <<= 1) {
#pragma unroll
        for (int uc = 0; uc < 2; ++uc)
#pragma unroll
        for (int ur = 0; ur < 2; ++ur)
#pragma unroll
        for (int reg = 0; reg < 4; ++reg)
#pragma unroll
        for (int o = 0; o < NOBJ; ++o)
            mm[uc][ur][reg][o] = fminf(mm[uc][ur][reg][o], __shfl_xor(mm[uc][ur][reg][o], s));
    }
    if (n == 0) {
#pragma unroll
        for (int uc = 0; uc < 2; ++uc)
#pragma unroll
        for (int ur = 0; ur < 2; ++ur)
#pragma unroll
        for (int reg = 0; reg < 4; ++reg) {
            const int qrow = i0 + ur;
            const int qcol = j0w + 16 * uc + quad * 4 + reg;
            unsigned int* op = out + ((size_t)(qrow * HW + qcol)) * NOBJ;
#pragma unroll
            for (int o = 0; o < NOBJ; ++o) {
                float v = fminf(fmaxf(mm[uc][ur][reg][o], 0.f), 1.0f);  // 1.0 = mask padding
                atomicMin(op + o, __float_as_uint(v));
            }
        }
    }
}

extern "C" void kernel_launch(void* const* d_in, const int* in_sizes, int n_in,
                              void* d_out, int out_size, void* d_ws, size_t ws_size,
                              hipStream_t stream) {
    const float* P      = (const float*)d_in[0];   // prev_frame_embedding [128,128,100]
    const float* Q      = (const float*)d_in[1];   // query_embedding      [128,128,100]
    const int*   labels = (const int*)d_in[2];     // prev_frame_labels    [128,128,1]
    const int*   gt     = (const int*)d_in[3];     // gt_ids [3]
    // d_in[4] = max_distance (always 15; compiled for MD=15)

    // Workspace layout (~8.5 MB):
    float* y2 = (float*)d_ws;                                   //  64 KB
    float* x2 = y2 + HW * HW;                                   //  64 KB
    signed char* Pq = (signed char*)(x2 + HW * HW);             // 4.19 MB (B image)
    signed char* Qa = Pq + (size_t)HW * HW * 256;               // 4.19 MB (A frags)
    unsigned int* out = (unsigned int*)d_out;

    vos_prep<<<2560, 256, 0, stream>>>(P, Q, Pq, Qa, y2, x2, out);
    vos_band<<<512, 256, 0, stream>>>(Pq, Qa, labels, gt, y2, x2, out);
}